// Round 15
// baseline (143.105 us; speedup 1.0000x reference)
//
#include <hip/hip_runtime.h>

#define BB 8
#define NN 2048
#define DD 768
#define KI 10
#define KR 5

typedef __attribute__((ext_vector_type(8))) _Float16 f16x8;
typedef __attribute__((ext_vector_type(4))) float f32x4;
typedef __attribute__((ext_vector_type(16))) float f32x16;

__device__ __forceinline__ void async_copy16(void* ldsp, const void* g) {
  __builtin_amdgcn_global_load_lds(
      (const __attribute__((address_space(1))) unsigned int*)g,
      (__attribute__((address_space(3))) unsigned int*)ldsp, 16, 0, 0);
}

__device__ __forceinline__ unsigned short f2h(float x) {
  _Float16 h = (_Float16)x;
  unsigned short u;
  __builtin_memcpy(&u, &h, 2);
  return u;
}

// ---------------- convert fp32 -> fp16 (single tensor each) ----------------
__global__ __launch_bounds__(256) void k_split(const float* __restrict__ q,
                                               const float* __restrict__ k,
                                               unsigned short* __restrict__ qH,
                                               unsigned short* __restrict__ kH) {
  const int n4 = BB * NN * DD / 4;
  const float4* src = (const float4*)(blockIdx.y ? k : q);
  ushort4* h = (ushort4*)(blockIdx.y ? kH : qH);
  for (int i = blockIdx.x * blockDim.x + threadIdx.x; i < n4;
       i += gridDim.x * blockDim.x) {
    float4 v = src[i];
    ushort4 hv;
    hv.x = f2h(v.x); hv.y = f2h(v.y); hv.z = f2h(v.z); hv.w = f2h(v.w);
    h[i] = hv;
  }
}

// ---------------- 128x128 MFMA kernel, fp16, K=768, 32x32x16 shape ----------------
// r14 structure; MFMA shape swapped to 32x32x16 (half the instruction count,
// higher ubench rate). A-frag: lane reads row (lane&31), k = ksub*16+(lane>>5)*8+j.
// C/D (HW-verified, dtype-indep): col=lane&31, row=(reg&3)+8*(reg>>2)+4*(lane>>5).
__global__ __launch_bounds__(256, 4) void k_mfma(const unsigned short* __restrict__ qH,
                                                 const unsigned short* __restrict__ kH,
                                                 float* __restrict__ pmT,
                                                 float* __restrict__ plT,
                                                 float* __restrict__ sdiag) {
  __shared__ short As[128 * 64];
  __shared__ short Bs[128 * 64];
  const int flat = blockIdx.y * 256 + blockIdx.x;
  const int nid = (flat & 7) * 256 + (flat >> 3);   // one batch per XCD
  const int b = nid >> 8;
  const int tile = nid & 255;
  const int tm = tile >> 4;
  const int tn = tile & 15;
  const int tid = threadIdx.x;
  const int w = tid >> 6, lane = tid & 63;
  const int wr = w >> 1, wc = w & 1;
  const int l31 = lane & 31, h32 = lane >> 5;

  int stageOff[4];
  char* ldsA[4];
  char* ldsB[4];
#pragma unroll
  for (int p = 0; p < 4; p++) {
    int L = w * 4096 + p * 1024 + lane * 16;
    int row = L >> 7;
    int s = (L >> 4) & 7;
    stageOff[p] = row * (DD * 2) + ((s ^ (row & 7)) << 4);
    ldsA[p] = (char*)As + w * 4096 + p * 1024;
    ldsB[p] = (char*)Bs + w * 4096 + p * 1024;
  }
  const char* A = (const char*)qH + ((size_t)b * NN + (size_t)tm * 128) * (DD * 2);
  const char* B = (const char*)kH + ((size_t)b * NN + (size_t)tn * 128) * (DD * 2);

  f32x16 acc[2][2];
#pragma unroll
  for (int i = 0; i < 2; i++)
#pragma unroll
    for (int j = 0; j < 2; j++)
#pragma unroll
      for (int e = 0; e < 16; e++) acc[i][j][e] = 0.f;

  // fragment row bases: A rows (q) for m-subtiles, B rows (k cols) for n-subtiles
  const int aoffm[2] = {(wr * 64 + 0 + l31) * 128, (wr * 64 + 32 + l31) * 128};
  const int boffn[2] = {(wc * 64 + 0 + l31) * 128, (wc * 64 + 32 + l31) * 128};
  const int l7 = lane & 7;
  const char* Ab = (const char*)As;
  const char* Bb = (const char*)Bs;

  for (int k0 = 0; k0 < DD * 2; k0 += 128) {   // 12 K-steps of 64 fp16
#pragma unroll
    for (int p = 0; p < 4; p++) async_copy16(ldsA[p], A + stageOff[p] + k0);
#pragma unroll
    for (int p = 0; p < 4; p++) async_copy16(ldsB[p], B + stageOff[p] + k0);
    __syncthreads();
#pragma unroll
    for (int ksub = 0; ksub < 4; ksub++) {     // 16 fp16 of K per sub-step
      const int sw = ((ksub * 2 + h32) ^ l7) << 4;
      f16x8 a0 = *(const f16x8*)(Ab + aoffm[0] + sw);
      f16x8 a1 = *(const f16x8*)(Ab + aoffm[1] + sw);
      f16x8 b0 = *(const f16x8*)(Bb + boffn[0] + sw);
      f16x8 b1 = *(const f16x8*)(Bb + boffn[1] + sw);
      acc[0][0] = __builtin_amdgcn_mfma_f32_32x32x16_f16(a0, b0, acc[0][0], 0, 0, 0);
      acc[0][1] = __builtin_amdgcn_mfma_f32_32x32x16_f16(a0, b1, acc[0][1], 0, 0, 0);
      acc[1][0] = __builtin_amdgcn_mfma_f32_32x32x16_f16(a1, b0, acc[1][0], 0, 0, 0);
      acc[1][1] = __builtin_amdgcn_mfma_f32_32x32x16_f16(a1, b1, acc[1][1], 0, 0, 0);
    }
    __syncthreads();
  }

  // fused diagonal extraction (tiles tm==tn, waves wr==wc, subtiles mi==ni)
  if (tm == tn && wr == wc) {
#pragma unroll
    for (int mi = 0; mi < 2; mi++) {
#pragma unroll
      for (int rg = 0; rg < 16; rg++) {
        const int rloc = (rg & 3) + 8 * (rg >> 2) + 4 * h32;
        if (l31 == rloc) {
          int row = tm * 128 + wr * 64 + mi * 32 + rloc;
          sdiag[b * NN + row] = acc[mi][mi][rg];
        }
      }
    }
  }

  // per-row partial max / sumexp over this wave's 64 cols (2 n-subtiles)
  // row r of subtile mi lives in half-wave h=(r>>2)&1, reg rg=(r&3)|((r>>3)<<2)
  float* pmB = pmT + ((size_t)b * NN + tm * 128 + wr * 64) * 32 + (tn * 2 + wc);
  float* plB = plT + ((size_t)b * NN + tm * 128 + wr * 64) * 32 + (tn * 2 + wc);
#pragma unroll
  for (int mi = 0; mi < 2; mi++) {
#pragma unroll
    for (int rg = 0; rg < 16; rg++) {
      float v0 = acc[mi][0][rg], v1 = acc[mi][1][rg];
      float mx = fmaxf(v0, v1);
      mx = fmaxf(mx, __shfl_xor(mx, 1));
      mx = fmaxf(mx, __shfl_xor(mx, 2));
      mx = fmaxf(mx, __shfl_xor(mx, 4));
      mx = fmaxf(mx, __shfl_xor(mx, 8));
      mx = fmaxf(mx, __shfl_xor(mx, 16));
      float sm = __expf(v0 - mx) + __expf(v1 - mx);
      sm += __shfl_xor(sm, 1);
      sm += __shfl_xor(sm, 2);
      sm += __shfl_xor(sm, 4);
      sm += __shfl_xor(sm, 8);
      sm += __shfl_xor(sm, 16);
      if (l31 == 0) {
        const int rloc = mi * 32 + (rg & 3) + 8 * (rg >> 2) + 4 * h32;
        pmB[rloc * 32] = mx;
        plB[rloc * 32] = sm;
      }
    }
  }
}

// ---------------- combine partials + diag softmax (coalesced float4 reads) ----------------
__global__ __launch_bounds__(256) void k_combine2(const float* __restrict__ pmT,
                                                  const float* __restrict__ plT,
                                                  const float* __restrict__ sdiag,
                                                  float* __restrict__ mA,
                                                  float* __restrict__ lA,
                                                  float* __restrict__ dg) {
  int idx = blockIdx.x * 256 + threadIdx.x;  // b*NN + row
  const float4* pm4 = (const float4*)(pmT + (size_t)idx * 32);
  const float4* pl4 = (const float4*)(plT + (size_t)idx * 32);
  float4 a[8];
#pragma unroll
  for (int i = 0; i < 8; i++) a[i] = pm4[i];
  float m = -INFINITY;
#pragma unroll
  for (int i = 0; i < 8; i++)
    m = fmaxf(m, fmaxf(fmaxf(a[i].x, a[i].y), fmaxf(a[i].z, a[i].w)));
  float l = 0.f;
#pragma unroll
  for (int i = 0; i < 8; i++) {
    float4 p = pl4[i];
    l += p.x * __expf(a[i].x - m) + p.y * __expf(a[i].y - m) +
         p.z * __expf(a[i].z - m) + p.w * __expf(a[i].w - m);
  }
  mA[idx] = m;
  lA[idx] = l;
  dg[idx] = __expf(sdiag[idx] - m) / l;
}

// ---------------- per-batch selection: shfl-reduce top-10 + LDS-staged rel dots ----------------
#define QPAD 772
__global__ __launch_bounds__(256) void k_select(const float* __restrict__ q,
                                                const float* __restrict__ k,
                                                const float* __restrict__ mArr,
                                                const float* __restrict__ lArr,
                                                const float* __restrict__ diag,
                                                int* __restrict__ inst,
                                                int* __restrict__ pairs) {
  const int b = blockIdx.x;
  const int tid = threadIdx.x;
  __shared__ float qs[KI * QPAD];
  __shared__ float ks[KI * QPAD];
  __shared__ float rv[4];
  __shared__ int ri[4];
  __shared__ int swin;
  __shared__ int schosen[KI];
  __shared__ int sinst[KI];
  __shared__ float srel[KI][KI];

  float v[8];
#pragma unroll
  for (int j = 0; j < 8; j++) v[j] = diag[b * NN + j * 256 + tid];

  const int wid = tid >> 6;
  const int lane = tid & 63;

  for (int t = 0; t < KI; t++) {
    float bv = -1e30f;
    int bj = 0;
#pragma unroll
    for (int j = 0; j < 8; j++)
      if (v[j] > bv) { bv = v[j]; bj = j; }
    int bi = bj * 256 + tid;
#pragma unroll
    for (int off = 1; off < 64; off <<= 1) {
      float ov = __shfl_xor(bv, off);
      int oi = __shfl_xor(bi, off);
      if (ov > bv || (ov == bv && oi < bi)) { bv = ov; bi = oi; }
    }
    if (lane == 0) { rv[wid] = bv; ri[wid] = bi; }
    __syncthreads();
    if (tid == 0) {
      float fv = rv[0]; int fi = ri[0];
#pragma unroll
      for (int wq = 1; wq < 4; wq++) {
        if (rv[wq] > fv || (rv[wq] == fv && ri[wq] < fi)) { fv = rv[wq]; fi = ri[wq]; }
      }
      schosen[t] = fi;
      swin = fi;
    }
    __syncthreads();
    const int win = swin;
    if (tid == (win & 255)) {
      const int jj = win >> 8;
#pragma unroll
      for (int j = 0; j < 8; j++)
        if (j == jj) v[j] = -1e30f;
    }
    __syncthreads();
  }
  if (tid == 0) {
    for (int i = 1; i < KI; i++) {
      int vv = schosen[i]; int j = i - 1;
      while (j >= 0 && schosen[j] > vv) { schosen[j + 1] = schosen[j]; j--; }
      schosen[j + 1] = vv;
    }
    for (int i = 0; i < KI; i++) { sinst[i] = schosen[i]; inst[b * KI + i] = schosen[i]; }
  }
  __syncthreads();

  for (int i = tid; i < KI * (DD / 4); i += 256) {
    const int row = i / (DD / 4);
    const int t4 = i - row * (DD / 4);
    const int g = sinst[row];
    float4 qv = ((const float4*)(q + ((size_t)b * NN + g) * DD))[t4];
    float4 kv = ((const float4*)(k + ((size_t)b * NN + g) * DD))[t4];
    const int base = row * QPAD + t4 * 4;
    qs[base + 0] = qv.x; qs[base + 1] = qv.y; qs[base + 2] = qv.z; qs[base + 3] = qv.w;
    ks[base + 0] = kv.x; ks[base + 1] = kv.y; ks[base + 2] = kv.z; ks[base + 3] = kv.w;
  }
  __syncthreads();

  if (tid < KI * KI) {
    const int a = tid / KI, c = tid % KI;
    const float4* qa = (const float4*)(qs + a * QPAD);
    const float4* kc = (const float4*)(ks + c * QPAD);
    float s = 0.f;
    for (int t = 0; t < DD / 4; t++) {
      float4 x = qa[t], y = kc[t];
      s += x.x * y.x + x.y * y.y + x.z * y.z + x.w * y.w;
    }
    const int ia = sinst[a];
    srel[a][c] = __expf(s - mArr[b * NN + ia]) / lArr[b * NN + ia];
  }
  __syncthreads();

  if (tid < KI) {
    int a = tid;
    float vv[KI];
    bool mk[KI];
    for (int c = 0; c < KI; c++) { vv[c] = srel[a][c]; mk[c] = false; }
    for (int r = 0; r < KR; r++) {
      float bv = -1e30f; int bi = -1;
      for (int c = 0; c < KI; c++)
        if (!mk[c] && vv[c] > bv) { bv = vv[c]; bi = c; }
      mk[bi] = true;
    }
    int r = 0;
    for (int c = 0; c < KI; c++)
      if (mk[c]) {
        int p = (b * KI * KR + a * KR + r) * 2;
        pairs[p] = sinst[a];
        pairs[p + 1] = sinst[c];
        r++;
      }
  }
}

// ---------------- gather outputs (400 blocks) ----------------
__global__ __launch_bounds__(192) void k_gather(const float* __restrict__ q,
                                                const int* __restrict__ pairs,
                                                float* __restrict__ out) {
  const int p = blockIdx.x;
  const int b = p / (KI * KR);
  const int si = pairs[p * 2];
  const int oi = pairs[p * 2 + 1];
  const int t = threadIdx.x;
  const float4* qs4 = (const float4*)(q + ((size_t)b * NN + si) * DD);
  const float4* qo4 = (const float4*)(q + ((size_t)b * NN + oi) * DD);
  float4 s4 = qs4[t];
  float4 o4 = qo4[t];
  float4* o = (float4*)out;
  const int SEC = BB * KI * KR * DD / 4;
  o[p * (DD / 4) + t] = s4;
  o[SEC + p * (DD / 4) + t] = o4;
  float4 r4;
  r4.x = s4.x + o4.x; r4.y = s4.y + o4.y; r4.z = s4.z + o4.z; r4.w = s4.w + o4.w;
  o[2 * SEC + p * (DD / 4) + t] = r4;
}

// ---------------- fallback fp32 row stats ----------------
#define TI 32
#define TJ 128
#define DKK 32

__global__ __launch_bounds__(256) void k_rowstats(const float* __restrict__ q,
                                                  const float* __restrict__ k,
                                                  float* __restrict__ mOut,
                                                  float* __restrict__ lOut) {
  __shared__ float qs[DKK][TI];
  __shared__ float ks[DKK][TJ];
  const int b = blockIdx.y;
  const int r0 = blockIdx.x * TI;
  const int tid = threadIdx.x;
  const int tx = tid & 31;
  const int ty = tid >> 5;
  const float* qb = q + (size_t)b * NN * DD;
  const float* kb = k + (size_t)b * NN * DD;

  float mr[4], lr[4];
#pragma unroll
  for (int i = 0; i < 4; i++) { mr[i] = -INFINITY; lr[i] = 0.f; }

  const int qrow = tid >> 3;
  const int qkk = (tid & 7) * 4;

  for (int c0 = 0; c0 < NN; c0 += TJ) {
    float acc[4][4];
#pragma unroll
    for (int i = 0; i < 4; i++)
#pragma unroll
      for (int j = 0; j < 4; j++) acc[i][j] = 0.f;

    for (int d0 = 0; d0 < DD; d0 += DKK) {
      {
        float4 v = *(const float4*)&qb[(r0 + qrow) * DD + d0 + qkk];
        qs[qkk + 0][qrow] = v.x; qs[qkk + 1][qrow] = v.y;
        qs[qkk + 2][qrow] = v.z; qs[qkk + 3][qrow] = v.w;
      }
#pragma unroll
      for (int p = 0; p < 4; p++) {
        int f = tid + p * 256;
        int col = f >> 3;
        int kk = (f & 7) * 4;
        float4 v = *(const float4*)&kb[(c0 + col) * DD + d0 + kk];
        ks[kk + 0][col] = v.x; ks[kk + 1][col] = v.y;
        ks[kk + 2][col] = v.z; ks[kk + 3][col] = v.w;
      }
      __syncthreads();
#pragma unroll
      for (int kk = 0; kk < DKK; kk++) {
        float4 a = *(const float4*)&qs[kk][ty * 4];
        float4 bb4 = *(const float4*)&ks[kk][tx * 4];
        float av[4] = {a.x, a.y, a.z, a.w};
        float bv[4] = {bb4.x, bb4.y, bb4.z, bb4.w};
#pragma unroll
        for (int i = 0; i < 4; i++)
#pragma unroll
          for (int j = 0; j < 4; j++)
            acc[i][j] = fmaf(av[i], bv[j], acc[i][j]);
      }
      __syncthreads();
    }
#pragma unroll
    for (int i = 0; i < 4; i++) {
      float vmax = fmaxf(fmaxf(acc[i][0], acc[i][1]), fmaxf(acc[i][2], acc[i][3]));
      float nm = fmaxf(mr[i], vmax);
      float s = __expf(acc[i][0] - nm) + __expf(acc[i][1] - nm) +
                __expf(acc[i][2] - nm) + __expf(acc[i][3] - nm);
      lr[i] = lr[i] * __expf(mr[i] - nm) + s;
      mr[i] = nm;
    }
  }
#pragma unroll
  for (int i = 0; i < 4; i++) {
    float m = mr[i], l = lr[i];
    for (int off = 1; off < 32; off <<= 1) {
      float om = __shfl_xor(m, off);
      float ol = __shfl_xor(l, off);
      float nm = fmaxf(m, om);
      l = l * __expf(m - nm) + ol * __expf(om - nm);
      m = nm;
    }
    if (tx == 0) {
      int row = r0 + ty * 4 + i;
      mOut[b * NN + row] = m;
      lOut[b * NN + row] = l;
    }
  }
}

// ---------------- fallback diagonal softmax ----------------
__global__ __launch_bounds__(256) void k_diag(const float* __restrict__ q,
                                              const float* __restrict__ k,
                                              const float* __restrict__ mArr,
                                              const float* __restrict__ lArr,
                                              float* __restrict__ diag) {
  const int b = blockIdx.y;
  const int row = blockIdx.x * 64 + (threadIdx.x >> 2);
  const int part = threadIdx.x & 3;
  const float4* q4 = (const float4*)(q + ((size_t)b * NN + row) * DD);
  const float4* k4 = (const float4*)(k + ((size_t)b * NN + row) * DD);
  float s = 0.f;
  for (int t = part; t < DD / 4; t += 4) {
    float4 a = q4[t], c = k4[t];
    s += a.x * c.x + a.y * c.y + a.z * c.z + a.w * c.w;
  }
  s += __shfl_xor(s, 1);
  s += __shfl_xor(s, 2);
  if (part == 0) {
    int idx = b * NN + row;
    diag[idx] = __expf(s - mArr[idx]) / lArr[idx];
  }
}

extern "C" void kernel_launch(void* const* d_in, const int* in_sizes, int n_in,
                              void* d_out, int out_size, void* d_ws, size_t ws_size,
                              hipStream_t stream) {
  const float* q = (const float*)d_in[0];
  const float* k = (const float*)d_in[1];
  char* ws = (char*)d_ws;

  const size_t S2 = (size_t)BB * NN * DD * 2;  // bytes of one fp16 tensor
  const size_t P = (size_t)BB * 32 * NN * 4;   // partial stats
  const size_t M4 = (size_t)BB * NN * 4;
  const size_t need = 2 * S2 + 2 * P + 4 * M4 + 65536;

  if (ws_size >= need) {
    unsigned short* qH = (unsigned short*)ws;
    unsigned short* kH = (unsigned short*)(ws + S2);
    float* pm = (float*)(ws + 2 * S2);
    float* pl = (float*)(ws + 2 * S2 + P);
    float* sdg = (float*)(ws + 2 * S2 + 2 * P);
    float* mA = sdg + BB * NN;
    float* lA = mA + BB * NN;
    float* dg = lA + BB * NN;
    int* inst = (int*)(dg + BB * NN);
    int* pairs = inst + BB * KI;

    k_split<<<dim3(2048, 2), 256, 0, stream>>>(q, k, qH, kH);
    k_mfma<<<dim3(256, BB), 256, 0, stream>>>(qH, kH, pm, pl, sdg);
    k_combine2<<<BB * NN / 256, 256, 0, stream>>>(pm, pl, sdg, mA, lA, dg);
    k_select<<<BB, 256, 0, stream>>>(q, k, mA, lA, dg, inst, pairs);
    k_gather<<<BB * KI * KR, 192, 0, stream>>>(q, pairs, (float*)d_out);
  } else {
    float* mA = (float*)ws;
    float* lA = mA + BB * NN;
    float* dg = lA + BB * NN;
    int* inst = (int*)(dg + BB * NN);
    int* pairs = inst + BB * KI;

    dim3 g1(NN / TI, BB);
    k_rowstats<<<g1, 256, 0, stream>>>(q, k, mA, lA);
    dim3 g1b(NN / 64, BB);
    k_diag<<<g1b, 256, 0, stream>>>(q, k, mA, lA, dg);
    k_select<<<BB, 256, 0, stream>>>(q, k, mA, lA, dg, inst, pairs);
    k_gather<<<BB * KI * KR, 192, 0, stream>>>(q, pairs, (float*)d_out);
  }
}

// Round 16
// 119.418 us; speedup vs baseline: 1.1983x; 1.1983x over previous
//
#include <hip/hip_runtime.h>

#define BB 8
#define NN 2048
#define DD 768
#define KI 10
#define KR 5

typedef __attribute__((ext_vector_type(8))) _Float16 f16x8;
typedef __attribute__((ext_vector_type(4))) float f32x4;

__device__ __forceinline__ void async_copy16(void* ldsp, const void* g) {
  __builtin_amdgcn_global_load_lds(
      (const __attribute__((address_space(1))) unsigned int*)g,
      (__attribute__((address_space(3))) unsigned int*)ldsp, 16, 0, 0);
}

__device__ __forceinline__ unsigned short f2h(float x) {
  _Float16 h = (_Float16)x;
  unsigned short u;
  __builtin_memcpy(&u, &h, 2);
  return u;
}

// ---------------- convert fp32 -> fp16 (single tensor each) ----------------
__global__ __launch_bounds__(256) void k_split(const float* __restrict__ q,
                                               const float* __restrict__ k,
                                               unsigned short* __restrict__ qH,
                                               unsigned short* __restrict__ kH) {
  const int n4 = BB * NN * DD / 4;
  const float4* src = (const float4*)(blockIdx.y ? k : q);
  ushort4* h = (ushort4*)(blockIdx.y ? kH : qH);
  for (int i = blockIdx.x * blockDim.x + threadIdx.x; i < n4;
       i += gridDim.x * blockDim.x) {
    float4 v = src[i];
    ushort4 hv;
    hv.x = f2h(v.x); hv.y = f2h(v.y); hv.z = f2h(v.z); hv.w = f2h(v.w);
    h[i] = hv;
  }
}

// ---------------- 128x128 MFMA kernel, fp16, K=768 (r14: 66.4us, 0 conflicts) ----------------
// 16x16x32 fragment pattern is the proven conflict-free arrangement under the
// XOR slot swizzle (r15's 32x32 shape: 6.3M bank conflicts, +25us — reverted).
__global__ __launch_bounds__(256, 4) void k_mfma(const unsigned short* __restrict__ qH,
                                                 const unsigned short* __restrict__ kH,
                                                 float* __restrict__ pmT,
                                                 float* __restrict__ plT,
                                                 float* __restrict__ sdiag) {
  __shared__ short As[128 * 64];
  __shared__ short Bs[128 * 64];
  const int flat = blockIdx.y * 256 + blockIdx.x;
  const int nid = (flat & 7) * 256 + (flat >> 3);   // one batch per XCD
  const int b = nid >> 8;
  const int tile = nid & 255;
  const int tm = tile >> 4;
  const int tn = tile & 15;
  const int tid = threadIdx.x;
  const int w = tid >> 6, lane = tid & 63;
  const int wr = w >> 1, wc = w & 1;
  const int l15 = lane & 15, g4 = lane >> 4;

  int stageOff[4];
  char* ldsA[4];
  char* ldsB[4];
#pragma unroll
  for (int p = 0; p < 4; p++) {
    int L = w * 4096 + p * 1024 + lane * 16;
    int row = L >> 7;
    int s = (L >> 4) & 7;
    stageOff[p] = row * (DD * 2) + ((s ^ (row & 7)) << 4);
    ldsA[p] = (char*)As + w * 4096 + p * 1024;
    ldsB[p] = (char*)Bs + w * 4096 + p * 1024;
  }
  const char* A = (const char*)qH + ((size_t)b * NN + (size_t)tm * 128) * (DD * 2);
  const char* B = (const char*)kH + ((size_t)b * NN + (size_t)tn * 128) * (DD * 2);

  f32x4 acc[4][4];
#pragma unroll
  for (int i = 0; i < 4; i++)
#pragma unroll
    for (int j = 0; j < 4; j++) acc[i][j] = (f32x4){0.f, 0.f, 0.f, 0.f};

  const int sw0 = ((g4) ^ (lane & 7)) << 4;
  const int sw1 = ((4 + g4) ^ (lane & 7)) << 4;
  int aoff[4], boff[4];
#pragma unroll
  for (int i = 0; i < 4; i++) {
    aoff[i] = (wr * 64 + i * 16 + l15) * 128;
    boff[i] = (wc * 64 + i * 16 + l15) * 128;
  }
  const char* Ab = (const char*)As;
  const char* Bb = (const char*)Bs;

  for (int k0 = 0; k0 < DD * 2; k0 += 128) {   // 12 K-steps of 64 fp16
#pragma unroll
    for (int p = 0; p < 4; p++) async_copy16(ldsA[p], A + stageOff[p] + k0);
#pragma unroll
    for (int p = 0; p < 4; p++) async_copy16(ldsB[p], B + stageOff[p] + k0);
    __syncthreads();
    {
      f16x8 af[4], bf[4];
#pragma unroll
      for (int mi = 0; mi < 4; mi++) af[mi] = *(const f16x8*)(Ab + aoff[mi] + sw0);
#pragma unroll
      for (int ni = 0; ni < 4; ni++) bf[ni] = *(const f16x8*)(Bb + boff[ni] + sw0);
#pragma unroll
      for (int mi = 0; mi < 4; mi++)
#pragma unroll
        for (int ni = 0; ni < 4; ni++)
          acc[mi][ni] = __builtin_amdgcn_mfma_f32_16x16x32_f16(af[mi], bf[ni],
                                                               acc[mi][ni], 0, 0, 0);
#pragma unroll
      for (int mi = 0; mi < 4; mi++) af[mi] = *(const f16x8*)(Ab + aoff[mi] + sw1);
#pragma unroll
      for (int ni = 0; ni < 4; ni++) bf[ni] = *(const f16x8*)(Bb + boff[ni] + sw1);
#pragma unroll
      for (int mi = 0; mi < 4; mi++)
#pragma unroll
        for (int ni = 0; ni < 4; ni++)
          acc[mi][ni] = __builtin_amdgcn_mfma_f32_16x16x32_f16(af[mi], bf[ni],
                                                               acc[mi][ni], 0, 0, 0);
    }
    __syncthreads();
  }

  // fused diagonal extraction (tiles tm==tn)
  if (tm == tn && wr == wc) {
#pragma unroll
    for (int mi = 0; mi < 4; mi++) {
#pragma unroll
      for (int rg = 0; rg < 4; rg++) {
        if (l15 == g4 * 4 + rg) {
          int row = tm * 128 + wr * 64 + mi * 16 + l15;
          sdiag[b * NN + row] = acc[mi][mi][rg];
        }
      }
    }
  }

  // transposed partial-stat write: [b][row][chunk], chunk = tn*2+wc
  float* pmB = pmT + ((size_t)b * NN + tm * 128 + wr * 64) * 32 + (tn * 2 + wc);
  float* plB = plT + ((size_t)b * NN + tm * 128 + wr * 64) * 32 + (tn * 2 + wc);
#pragma unroll
  for (int mi = 0; mi < 4; mi++) {
#pragma unroll
    for (int r = 0; r < 4; r++) {
      float v0 = acc[mi][0][r], v1 = acc[mi][1][r], v2 = acc[mi][2][r], v3 = acc[mi][3][r];
      float mx = fmaxf(fmaxf(v0, v1), fmaxf(v2, v3));
      mx = fmaxf(mx, __shfl_xor(mx, 1));
      mx = fmaxf(mx, __shfl_xor(mx, 2));
      mx = fmaxf(mx, __shfl_xor(mx, 4));
      mx = fmaxf(mx, __shfl_xor(mx, 8));
      float sm = __expf(v0 - mx) + __expf(v1 - mx) + __expf(v2 - mx) + __expf(v3 - mx);
      sm += __shfl_xor(sm, 1);
      sm += __shfl_xor(sm, 2);
      sm += __shfl_xor(sm, 4);
      sm += __shfl_xor(sm, 8);
      if (l15 == 0) {
        pmB[(mi * 16 + g4 * 4 + r) * 32] = mx;
        plB[(mi * 16 + g4 * 4 + r) * 32] = sm;
      }
    }
  }
}

// ---------------- combine partials + diag softmax (coalesced float4 reads) ----------------
__global__ __launch_bounds__(256) void k_combine2(const float* __restrict__ pmT,
                                                  const float* __restrict__ plT,
                                                  const float* __restrict__ sdiag,
                                                  float* __restrict__ mA,
                                                  float* __restrict__ lA,
                                                  float* __restrict__ dg) {
  int idx = blockIdx.x * 256 + threadIdx.x;  // b*NN + row
  const float4* pm4 = (const float4*)(pmT + (size_t)idx * 32);
  const float4* pl4 = (const float4*)(plT + (size_t)idx * 32);
  float4 a[8];
#pragma unroll
  for (int i = 0; i < 8; i++) a[i] = pm4[i];
  float m = -INFINITY;
#pragma unroll
  for (int i = 0; i < 8; i++)
    m = fmaxf(m, fmaxf(fmaxf(a[i].x, a[i].y), fmaxf(a[i].z, a[i].w)));
  float l = 0.f;
#pragma unroll
  for (int i = 0; i < 8; i++) {
    float4 p = pl4[i];
    l += p.x * __expf(a[i].x - m) + p.y * __expf(a[i].y - m) +
         p.z * __expf(a[i].z - m) + p.w * __expf(a[i].w - m);
  }
  mA[idx] = m;
  lA[idx] = l;
  dg[idx] = __expf(sdiag[idx] - m) / l;
}

// ---------------- per-batch selection: shfl-reduce top-10 + LDS-staged rel dots ----------------
#define QPAD 772
__global__ __launch_bounds__(256) void k_select(const float* __restrict__ q,
                                                const float* __restrict__ k,
                                                const float* __restrict__ mArr,
                                                const float* __restrict__ lArr,
                                                const float* __restrict__ diag,
                                                int* __restrict__ inst,
                                                int* __restrict__ pairs) {
  const int b = blockIdx.x;
  const int tid = threadIdx.x;
  __shared__ float qs[KI * QPAD];
  __shared__ float ks[KI * QPAD];
  __shared__ float rv[4];
  __shared__ int ri[4];
  __shared__ int swin;
  __shared__ int schosen[KI];
  __shared__ int sinst[KI];
  __shared__ float srel[KI][KI];

  float v[8];
#pragma unroll
  for (int j = 0; j < 8; j++) v[j] = diag[b * NN + j * 256 + tid];

  const int wid = tid >> 6;
  const int lane = tid & 63;

  for (int t = 0; t < KI; t++) {
    float bv = -1e30f;
    int bj = 0;
#pragma unroll
    for (int j = 0; j < 8; j++)
      if (v[j] > bv) { bv = v[j]; bj = j; }
    int bi = bj * 256 + tid;
#pragma unroll
    for (int off = 1; off < 64; off <<= 1) {
      float ov = __shfl_xor(bv, off);
      int oi = __shfl_xor(bi, off);
      if (ov > bv || (ov == bv && oi < bi)) { bv = ov; bi = oi; }
    }
    if (lane == 0) { rv[wid] = bv; ri[wid] = bi; }
    __syncthreads();
    if (tid == 0) {
      float fv = rv[0]; int fi = ri[0];
#pragma unroll
      for (int wq = 1; wq < 4; wq++) {
        if (rv[wq] > fv || (rv[wq] == fv && ri[wq] < fi)) { fv = rv[wq]; fi = ri[wq]; }
      }
      schosen[t] = fi;
      swin = fi;
    }
    __syncthreads();
    const int win = swin;
    if (tid == (win & 255)) {
      const int jj = win >> 8;
#pragma unroll
      for (int j = 0; j < 8; j++)
        if (j == jj) v[j] = -1e30f;
    }
    __syncthreads();
  }
  if (tid == 0) {
    for (int i = 1; i < KI; i++) {
      int vv = schosen[i]; int j = i - 1;
      while (j >= 0 && schosen[j] > vv) { schosen[j + 1] = schosen[j]; j--; }
      schosen[j + 1] = vv;
    }
    for (int i = 0; i < KI; i++) { sinst[i] = schosen[i]; inst[b * KI + i] = schosen[i]; }
  }
  __syncthreads();

  for (int i = tid; i < KI * (DD / 4); i += 256) {
    const int row = i / (DD / 4);
    const int t4 = i - row * (DD / 4);
    const int g = sinst[row];
    float4 qv = ((const float4*)(q + ((size_t)b * NN + g) * DD))[t4];
    float4 kv = ((const float4*)(k + ((size_t)b * NN + g) * DD))[t4];
    const int base = row * QPAD + t4 * 4;
    qs[base + 0] = qv.x; qs[base + 1] = qv.y; qs[base + 2] = qv.z; qs[base + 3] = qv.w;
    ks[base + 0] = kv.x; ks[base + 1] = kv.y; ks[base + 2] = kv.z; ks[base + 3] = kv.w;
  }
  __syncthreads();

  if (tid < KI * KI) {
    const int a = tid / KI, c = tid % KI;
    const float4* qa = (const float4*)(qs + a * QPAD);
    const float4* kc = (const float4*)(ks + c * QPAD);
    float s = 0.f;
    for (int t = 0; t < DD / 4; t++) {
      float4 x = qa[t], y = kc[t];
      s += x.x * y.x + x.y * y.y + x.z * y.z + x.w * y.w;
    }
    const int ia = sinst[a];
    srel[a][c] = __expf(s - mArr[b * NN + ia]) / lArr[b * NN + ia];
  }
  __syncthreads();

  if (tid < KI) {
    int a = tid;
    float vv[KI];
    bool mk[KI];
    for (int c = 0; c < KI; c++) { vv[c] = srel[a][c]; mk[c] = false; }
    for (int r = 0; r < KR; r++) {
      float bv = -1e30f; int bi = -1;
      for (int c = 0; c < KI; c++)
        if (!mk[c] && vv[c] > bv) { bv = vv[c]; bi = c; }
      mk[bi] = true;
    }
    int r = 0;
    for (int c = 0; c < KI; c++)
      if (mk[c]) {
        int p = (b * KI * KR + a * KR + r) * 2;
        pairs[p] = sinst[a];
        pairs[p + 1] = sinst[c];
        r++;
      }
  }
}

// ---------------- gather outputs (400 blocks) ----------------
__global__ __launch_bounds__(192) void k_gather(const float* __restrict__ q,
                                                const int* __restrict__ pairs,
                                                float* __restrict__ out) {
  const int p = blockIdx.x;
  const int b = p / (KI * KR);
  const int si = pairs[p * 2];
  const int oi = pairs[p * 2 + 1];
  const int t = threadIdx.x;
  const float4* qs4 = (const float4*)(q + ((size_t)b * NN + si) * DD);
  const float4* qo4 = (const float4*)(q + ((size_t)b * NN + oi) * DD);
  float4 s4 = qs4[t];
  float4 o4 = qo4[t];
  float4* o = (float4*)out;
  const int SEC = BB * KI * KR * DD / 4;
  o[p * (DD / 4) + t] = s4;
  o[SEC + p * (DD / 4) + t] = o4;
  float4 r4;
  r4.x = s4.x + o4.x; r4.y = s4.y + o4.y; r4.z = s4.z + o4.z; r4.w = s4.w + o4.w;
  o[2 * SEC + p * (DD / 4) + t] = r4;
}

// ---------------- fallback fp32 row stats ----------------
#define TI 32
#define TJ 128
#define DKK 32

__global__ __launch_bounds__(256) void k_rowstats(const float* __restrict__ q,
                                                  const float* __restrict__ k,
                                                  float* __restrict__ mOut,
                                                  float* __restrict__ lOut) {
  __shared__ float qs[DKK][TI];
  __shared__ float ks[DKK][TJ];
  const int b = blockIdx.y;
  const int r0 = blockIdx.x * TI;
  const int tid = threadIdx.x;
  const int tx = tid & 31;
  const int ty = tid >> 5;
  const float* qb = q + (size_t)b * NN * DD;
  const float* kb = k + (size_t)b * NN * DD;

  float mr[4], lr[4];
#pragma unroll
  for (int i = 0; i < 4; i++) { mr[i] = -INFINITY; lr[i] = 0.f; }

  const int qrow = tid >> 3;
  const int qkk = (tid & 7) * 4;

  for (int c0 = 0; c0 < NN; c0 += TJ) {
    float acc[4][4];
#pragma unroll
    for (int i = 0; i < 4; i++)
#pragma unroll
      for (int j = 0; j < 4; j++) acc[i][j] = 0.f;

    for (int d0 = 0; d0 < DD; d0 += DKK) {
      {
        float4 v = *(const float4*)&qb[(r0 + qrow) * DD + d0 + qkk];
        qs[qkk + 0][qrow] = v.x; qs[qkk + 1][qrow] = v.y;
        qs[qkk + 2][qrow] = v.z; qs[qkk + 3][qrow] = v.w;
      }
#pragma unroll
      for (int p = 0; p < 4; p++) {
        int f = tid + p * 256;
        int col = f >> 3;
        int kk = (f & 7) * 4;
        float4 v = *(const float4*)&kb[(c0 + col) * DD + d0 + kk];
        ks[kk + 0][col] = v.x; ks[kk + 1][col] = v.y;
        ks[kk + 2][col] = v.z; ks[kk + 3][col] = v.w;
      }
      __syncthreads();
#pragma unroll
      for (int kk = 0; kk < DKK; kk++) {
        float4 a = *(const float4*)&qs[kk][ty * 4];
        float4 bb4 = *(const float4*)&ks[kk][tx * 4];
        float av[4] = {a.x, a.y, a.z, a.w};
        float bv[4] = {bb4.x, bb4.y, bb4.z, bb4.w};
#pragma unroll
        for (int i = 0; i < 4; i++)
#pragma unroll
          for (int j = 0; j < 4; j++)
            acc[i][j] = fmaf(av[i], bv[j], acc[i][j]);
      }
      __syncthreads();
    }
#pragma unroll
    for (int i = 0; i < 4; i++) {
      float vmax = fmaxf(fmaxf(acc[i][0], acc[i][1]), fmaxf(acc[i][2], acc[i][3]));
      float nm = fmaxf(mr[i], vmax);
      float s = __expf(acc[i][0] - nm) + __expf(acc[i][1] - nm) +
                __expf(acc[i][2] - nm) + __expf(acc[i][3] - nm);
      lr[i] = lr[i] * __expf(mr[i] - nm) + s;
      mr[i] = nm;
    }
  }
#pragma unroll
  for (int i = 0; i < 4; i++) {
    float m = mr[i], l = lr[i];
    for (int off = 1; off < 32; off <<= 1) {
      float om = __shfl_xor(m, off);
      float ol = __shfl_xor(l, off);
      float nm = fmaxf(m, om);
      l = l * __expf(m - nm) + ol * __expf(om - nm);
      m = nm;
    }
    if (tx == 0) {
      int row = r0 + ty * 4 + i;
      mOut[b * NN + row] = m;
      lOut[b * NN + row] = l;
    }
  }
}

// ---------------- fallback diagonal softmax ----------------
__global__ __launch_bounds__(256) void k_diag(const float* __restrict__ q,
                                              const float* __restrict__ k,
                                              const float* __restrict__ mArr,
                                              const float* __restrict__ lArr,
                                              float* __restrict__ diag) {
  const int b = blockIdx.y;
  const int row = blockIdx.x * 64 + (threadIdx.x >> 2);
  const int part = threadIdx.x & 3;
  const float4* q4 = (const float4*)(q + ((size_t)b * NN + row) * DD);
  const float4* k4 = (const float4*)(k + ((size_t)b * NN + row) * DD);
  float s = 0.f;
  for (int t = part; t < DD / 4; t += 4) {
    float4 a = q4[t], c = k4[t];
    s += a.x * c.x + a.y * c.y + a.z * c.z + a.w * c.w;
  }
  s += __shfl_xor(s, 1);
  s += __shfl_xor(s, 2);
  if (part == 0) {
    int idx = b * NN + row;
    diag[idx] = __expf(s - mArr[idx]) / lArr[idx];
  }
}

extern "C" void kernel_launch(void* const* d_in, const int* in_sizes, int n_in,
                              void* d_out, int out_size, void* d_ws, size_t ws_size,
                              hipStream_t stream) {
  const float* q = (const float*)d_in[0];
  const float* k = (const float*)d_in[1];
  char* ws = (char*)d_ws;

  const size_t S2 = (size_t)BB * NN * DD * 2;  // bytes of one fp16 tensor
  const size_t P = (size_t)BB * 32 * NN * 4;   // partial stats
  const size_t M4 = (size_t)BB * NN * 4;
  const size_t need = 2 * S2 + 2 * P + 4 * M4 + 65536;

  if (ws_size >= need) {
    unsigned short* qH = (unsigned short*)ws;
    unsigned short* kH = (unsigned short*)(ws + S2);
    float* pm = (float*)(ws + 2 * S2);
    float* pl = (float*)(ws + 2 * S2 + P);
    float* sdg = (float*)(ws + 2 * S2 + 2 * P);
    float* mA = sdg + BB * NN;
    float* lA = mA + BB * NN;
    float* dg = lA + BB * NN;
    int* inst = (int*)(dg + BB * NN);
    int* pairs = inst + BB * KI;

    k_split<<<dim3(2048, 2), 256, 0, stream>>>(q, k, qH, kH);
    k_mfma<<<dim3(256, BB), 256, 0, stream>>>(qH, kH, pm, pl, sdg);
    k_combine2<<<BB * NN / 256, 256, 0, stream>>>(pm, pl, sdg, mA, lA, dg);
    k_select<<<BB, 256, 0, stream>>>(q, k, mA, lA, dg, inst, pairs);
    k_gather<<<BB * KI * KR, 192, 0, stream>>>(q, pairs, (float*)d_out);
  } else {
    float* mA = (float*)ws;
    float* lA = mA + BB * NN;
    float* dg = lA + BB * NN;
    int* inst = (int*)(dg + BB * NN);
    int* pairs = inst + BB * KI;

    dim3 g1(NN / TI, BB);
    k_rowstats<<<g1, 256, 0, stream>>>(q, k, mA, lA);
    dim3 g1b(NN / 64, BB);
    k_diag<<<g1b, 256, 0, stream>>>(q, k, mA, lA, dg);
    k_select<<<BB, 256, 0, stream>>>(q, k, mA, lA, dg, inst, pairs);
    k_gather<<<BB * KI * KR, 192, 0, stream>>>(q, pairs, (float*)d_out);
  }
}